// Round 11
// baseline (312.677 us; speedup 1.0000x reference)
//
#include <hip/hip_runtime.h>

#define N_NODES 50000
#define E_EDGES 800000
#define D_INF   128
#define D_HIDF  512
#define D_OUTF  128
#define SCAN_NB ((N_NODES + 255) / 256)   // 196 blocks
#define MBLKS   ((N_NODES + 255) / 256)   // 196 row-blocks per GEMM (256-row tiles)
#define NB_CAST ((N_NODES * D_INF / 8 + 255) / 256)   // 3125
#define NB_HIST ((E_EDGES + 255) / 256)               // 3125
#define NB_W    ((128 * 512 + 255) / 256)             // 256

typedef unsigned short u16;
typedef __attribute__((ext_vector_type(8))) short short8;
typedef __attribute__((ext_vector_type(4))) float floatx4;

__device__ __forceinline__ u16 f2bf(float f) {
    union { float f; unsigned u; } v; v.f = f;
    unsigned r = (v.u + 0x7fffu + ((v.u >> 16) & 1u)) >> 16;
    return (u16)r;
}
__device__ __forceinline__ float bf2f(u16 b) {
    union { unsigned u; float f; } v; v.u = ((unsigned)b) << 16; return v.f;
}

// ---------------- merged prep: cast v->bf16 | hist+pos | weight transpose ----------------
__global__ void prep_kernel(const float* __restrict__ v, u16* __restrict__ vbf,
                            const int* __restrict__ dst, int* __restrict__ counts,
                            int* __restrict__ pos,
                            const float* __restrict__ W1, const float* __restrict__ W2,
                            u16* __restrict__ W1t, u16* __restrict__ W2t) {
    int b = blockIdx.x, tid = threadIdx.x;
    if (b < NB_CAST) {
        int i = b * 256 + tid;                    // exactly 800,000
        const float4 a = ((const float4*)v)[i * 2];
        const float4 bb = ((const float4*)v)[i * 2 + 1];
        u16 o[8];
        o[0] = f2bf(a.x);  o[1] = f2bf(a.y);  o[2] = f2bf(a.z);  o[3] = f2bf(a.w);
        o[4] = f2bf(bb.x); o[5] = f2bf(bb.y); o[6] = f2bf(bb.z); o[7] = f2bf(bb.w);
        ((float4*)vbf)[i] = *(const float4*)o;
    } else if (b < NB_CAST + NB_HIST) {
        int e = (b - NB_CAST) * 256 + tid;        // exactly 800,000
        pos[e] = atomicAdd(&counts[dst[e]], 1);
    } else {
        int idx = (b - NB_CAST - NB_HIST) * 256 + tid;   // exactly 65,536
        int k1 = idx >> 9, n1 = idx & 511;        // W1 [128][512]
        W1t[n1 * 128 + k1] = f2bf(W1[idx]);
        int k2 = idx >> 7, n2 = idx & 127;        // W2 [512][128]
        W2t[n2 * 512 + k2] = f2bf(W2[idx]);
    }
}

// ---------------- scan phase 1: per-block sums ----------------
__global__ __launch_bounds__(256) void reduce_kernel(const int* __restrict__ counts,
                                                     int* __restrict__ block_sums) {
    __shared__ int lsum[4];
    int tid = threadIdx.x;
    int gid = blockIdx.x * 256 + tid;
    int s = (gid < N_NODES) ? counts[gid] : 0;
#pragma unroll
    for (int off = 32; off; off >>= 1) s += __shfl_down(s, off);
    if ((tid & 63) == 0) lsum[tid >> 6] = s;
    __syncthreads();
    if (tid == 0) block_sums[blockIdx.x] = lsum[0] + lsum[1] + lsum[2] + lsum[3];
}

// ---------------- scan phase 2 (merged): local scan + redundant block-sum scan ----------------
__global__ __launch_bounds__(256) void scan_final(const int* __restrict__ counts,
                                                  const int* __restrict__ block_sums,
                                                  int* __restrict__ row_start) {
    __shared__ int sh[256];
    __shared__ int bs[256];
    int tid = threadIdx.x;
    int gid = blockIdx.x * 256 + tid;
    sh[tid] = (gid < N_NODES) ? counts[gid] : 0;
    bs[tid] = (tid < SCAN_NB) ? block_sums[tid] : 0;
    __syncthreads();
    for (int off = 1; off < 256; off <<= 1) {
        int t1 = (tid >= off) ? sh[tid - off] : 0;
        int t2 = (tid >= off) ? bs[tid - off] : 0;
        __syncthreads();
        sh[tid] += t1;
        bs[tid] += t2;
        __syncthreads();
    }
    int boff = (blockIdx.x == 0) ? 0 : bs[blockIdx.x - 1];
    int excl = (tid == 0) ? 0 : sh[tid - 1];
    if (gid < N_NODES) row_start[gid] = boff + excl;
    if (gid == 0) row_start[N_NODES] = E_EDGES;
}

// ---------------- CSR fill — no atomics ----------------
__global__ void fill_kernel(const int* __restrict__ src, const int* __restrict__ dst,
                            const float* __restrict__ w, const int* __restrict__ pos,
                            const int* __restrict__ row_start,
                            int2* __restrict__ csr_ew) {
    int e = blockIdx.x * blockDim.x + threadIdx.x;
    if (e >= E_EDGES) return;
    int d = dst[e];
    int idx = row_start[d] + pos[e];
    int2 rec;
    rec.x = src[e];
    rec.y = __float_as_int(w[e]);
    csr_ew[idx] = rec;
}

// ---------------- gather: 16 lanes/node, ushort8 (16B) per lane, 2-edge unroll ----------
__global__ __launch_bounds__(256) void gather_kernel(const u16* __restrict__ vbf,
                                                     const int* __restrict__ row_start,
                                                     const int2* __restrict__ csr_ew,
                                                     const float* __restrict__ eps_p,
                                                     u16* __restrict__ vagg) {
    int node = blockIdx.x * 16 + (threadIdx.x >> 4);
    if (node >= N_NODES) return;
    int c8 = (threadIdx.x & 15) << 3;
    int beg = row_start[node];
    int end = row_start[node + 1];
    float a[8] = {};
    int j = beg;
    for (; j + 1 < end; j += 2) {
        int2 e0 = csr_ew[j];
        int2 e1 = csr_ew[j + 1];
        float w0 = __int_as_float(e0.y);
        float w1 = __int_as_float(e1.y);
        float4 r0 = *(const float4*)(vbf + (size_t)e0.x * D_INF + c8);
        float4 r1 = *(const float4*)(vbf + (size_t)e1.x * D_INF + c8);
        const u16* p0 = (const u16*)&r0;
        const u16* p1 = (const u16*)&r1;
#pragma unroll
        for (int t = 0; t < 8; ++t) a[t] += w0 * bf2f(p0[t]);
#pragma unroll
        for (int t = 0; t < 8; ++t) a[t] += w1 * bf2f(p1[t]);
    }
    if (j < end) {
        int2 e0 = csr_ew[j];
        float w0 = __int_as_float(e0.y);
        float4 r0 = *(const float4*)(vbf + (size_t)e0.x * D_INF + c8);
        const u16* p0 = (const u16*)&r0;
#pragma unroll
        for (int t = 0; t < 8; ++t) a[t] += w0 * bf2f(p0[t]);
    }
    float e = eps_p[0];
    float4 rn = *(const float4*)(vbf + (size_t)node * D_INF + c8);
    const u16* pn = (const u16*)&rn;
    u16 o[8];
#pragma unroll
    for (int t = 0; t < 8; ++t) o[t] = f2bf(a[t] + e * bf2f(pn[t]));
    *(float4*)(vagg + (size_t)node * D_INF + c8) = *(const float4*)o;
}

// ---------------- MFMA GEMM + bias + per-block BN partials, LDS-coalesced bf16 out ----------
template<int MT, int NT, int FUSE_A_BN>
__global__ __launch_bounds__(512) void mfma_gemm_bn(
        const u16* __restrict__ A, const u16* __restrict__ Bt,
        const float* __restrict__ bias,
        const float* __restrict__ a_scale, const float* __restrict__ a_shift,
        u16* __restrict__ Cout,
        float* __restrict__ psum, float* __restrict__ psq,
        int M, int Ncols, int K) {
    constexpr int NJ = NT / 32;
    constexpr int STG = (MT + NT) * 96;
    constexpr int SMEM_BYTES = (STG > 34816) ? STG : 34816;
    __shared__ __align__(16) char smem_raw[SMEM_BYTES];
    u16* As = (u16*)smem_raw;
    u16* Bs = As + MT * 48;
    const int bm = blockIdx.y * MT;
    const int bn = blockIdx.x * NT;
    const int tid = threadIdx.x;
    const int wave = tid >> 6, lane = tid & 63;
    const int wr = wave >> 1, wc = wave & 1;
    const int wm = wr * 64;
    const int wn = wc * (NT / 2);
    const int lm = lane & 15, quad = lane >> 4;

    floatx4 acc[4][NJ] = {};

    const int ksteps = K >> 5;
    for (int ks = 0; ks < ksteps; ++ks) {
        const int k0 = ks << 5;
        for (int c = tid; c < (MT + NT) * 4; c += 512) {
            int r = c >> 2;
            int kk = (c & 3) << 3;
            if (r < MT) {
                int row = bm + r;
                float4 av = make_float4(0.f, 0.f, 0.f, 0.f);
                if (row < M) {
                    av = *(const float4*)(A + (size_t)row * K + k0 + kk);
                    if (FUSE_A_BN) {
                        u16* ab = (u16*)&av;
                        const float4 s0 = *(const float4*)(a_scale + k0 + kk);
                        const float4 s1 = *(const float4*)(a_scale + k0 + kk + 4);
                        const float4 h0 = *(const float4*)(a_shift + k0 + kk);
                        const float4 h1 = *(const float4*)(a_shift + k0 + kk + 4);
                        ab[0] = f2bf(fmaxf(0.f, bf2f(ab[0]) * s0.x + h0.x));
                        ab[1] = f2bf(fmaxf(0.f, bf2f(ab[1]) * s0.y + h0.y));
                        ab[2] = f2bf(fmaxf(0.f, bf2f(ab[2]) * s0.z + h0.z));
                        ab[3] = f2bf(fmaxf(0.f, bf2f(ab[3]) * s0.w + h0.w));
                        ab[4] = f2bf(fmaxf(0.f, bf2f(ab[4]) * s1.x + h1.x));
                        ab[5] = f2bf(fmaxf(0.f, bf2f(ab[5]) * s1.y + h1.y));
                        ab[6] = f2bf(fmaxf(0.f, bf2f(ab[6]) * s1.z + h1.z));
                        ab[7] = f2bf(fmaxf(0.f, bf2f(ab[7]) * s1.w + h1.w));
                    }
                }
                *(float4*)&As[r * 48 + kk] = av;
            } else {
                int rb = r - MT;
                *(float4*)&Bs[rb * 48 + kk] =
                    *(const float4*)(Bt + (size_t)(bn + rb) * K + k0 + kk);
            }
        }
        __syncthreads();
        short8 af[4], bfr[NJ];
#pragma unroll
        for (int i = 0; i < 4; ++i)
            af[i] = *(const short8*)&As[(wm + i * 16 + lm) * 48 + quad * 8];
#pragma unroll
        for (int j = 0; j < NJ; ++j)
            bfr[j] = *(const short8*)&Bs[(wn + j * 16 + lm) * 48 + quad * 8];
#pragma unroll
        for (int i = 0; i < 4; ++i)
#pragma unroll
            for (int j = 0; j < NJ; ++j)
                acc[i][j] = __builtin_amdgcn_mfma_f32_16x16x32_bf16(af[i], bfr[j], acc[i][j], 0, 0, 0);
        __syncthreads();
    }

    // ---- per-block BN partials ----
    float* redS = (float*)smem_raw;
    float* redQ = redS + NT;
    if (tid < NT) { redS[tid] = 0.f; redQ[tid] = 0.f; }
    __syncthreads();
    float bjv[NJ];
#pragma unroll
    for (int j = 0; j < NJ; ++j) {
        int cl = wn + j * 16 + lm;
        bjv[j] = bias[bn + cl];
        float s = 0.f, q = 0.f;
#pragma unroll
        for (int i = 0; i < 4; ++i) {
            int row0 = bm + wm + i * 16 + quad * 4;
#pragma unroll
            for (int r = 0; r < 4; ++r) {
                if (row0 + r < M) {
                    float x = acc[i][j][r] + bjv[j];
                    s += x; q += x * x;
                }
            }
        }
        s += __shfl_xor(s, 16); q += __shfl_xor(q, 16);
        s += __shfl_xor(s, 32); q += __shfl_xor(q, 32);
        if (quad == 0) {
            atomicAdd(&redS[cl], s);
            atomicAdd(&redQ[cl], q);
        }
    }
    __syncthreads();
    if (tid < NT) {
        psum[(size_t)blockIdx.y * Ncols + bn + tid] = redS[tid];
        psq [(size_t)blockIdx.y * Ncols + bn + tid] = redQ[tid];
    }

    // ---- coalesced bf16 output via LDS obuf: passes of 128 rows x 64 cols ----
    float* obuf = (float*)smem_raw;
    constexpr int RH = MT / 128;
    constexpr int JH = NT / 64;
#pragma unroll
    for (int rh = 0; rh < RH; ++rh) {
#pragma unroll
        for (int jh = 0; jh < (JH ? JH : 1); ++jh) {
            __syncthreads();
            bool part = ((wr >> 1) == rh) && (NT == 64 || wc == jh);
            if (part) {
                int rbase = wm - rh * 128;
#pragma unroll
                for (int i = 0; i < 4; ++i)
#pragma unroll
                    for (int j = 0; j < NJ; ++j) {
                        int cp = (NT == 128) ? (j * 16 + lm) : (wn + j * 16 + lm);
#pragma unroll
                        for (int r = 0; r < 4; ++r)
                            obuf[(rbase + i * 16 + quad * 4 + r) * 68 + cp] =
                                acc[i][j][r] + bjv[j];
                    }
            }
            __syncthreads();
            int lr = tid >> 2;
            int seg = (tid & 3) << 4;
            int grow = bm + rh * 128 + lr;
            if (grow < M) {
                u16 ob[16];
#pragma unroll
                for (int t = 0; t < 4; ++t) {
                    float4 f = *(float4*)&obuf[lr * 68 + seg + t * 4];
                    ob[t * 4 + 0] = f2bf(f.x);
                    ob[t * 4 + 1] = f2bf(f.y);
                    ob[t * 4 + 2] = f2bf(f.z);
                    ob[t * 4 + 3] = f2bf(f.w);
                }
                u16* dstp = Cout + (size_t)grow * Ncols + bn + jh * 64 + seg;
                *(float4*)dstp       = *(float4*)(ob);
                *(float4*)(dstp + 8) = *(float4*)(ob + 8);
            }
        }
    }
}

// ---------------- BN1 finalize (parallel) ----------------
__global__ __launch_bounds__(1024) void bn_finalize_kernel(
        const float* __restrict__ psum, const float* __restrict__ psq,
        const float* __restrict__ gamma, const float* __restrict__ beta,
        float* __restrict__ scale, float* __restrict__ shift,
        int nblocks, int Ncols, float inv_n) {
    __shared__ float shS[16][64];
    __shared__ float shQ[16][64];
    const int tx = threadIdx.x;
    const int ty = threadIdx.y;
    const int c = blockIdx.x * 64 + tx;
    float s = 0.f, q = 0.f;
    for (int b = ty; b < nblocks; b += 16) {
        s += psum[(size_t)b * Ncols + c];
        q += psq [(size_t)b * Ncols + c];
    }
    shS[ty][tx] = s;
    shQ[ty][tx] = q;
    __syncthreads();
    if (ty == 0) {
        float S = 0.f, Q = 0.f;
#pragma unroll
        for (int r = 0; r < 16; ++r) { S += shS[r][tx]; Q += shQ[r][tx]; }
        float m = S * inv_n;
        float var = Q * inv_n - m * m;
        float rs = rsqrtf(var + 1e-5f);
        float sc = gamma[c] * rs;
        scale[c] = sc;
        shift[c] = beta[c] - sc * m;
    }
}

// ---------------- BN2 fused finalize+apply: redundant per-block reduce, then apply slice ----
__global__ __launch_bounds__(256) void bn2_fused_kernel(
        const float* __restrict__ psum, const float* __restrict__ psq,
        const float* __restrict__ gamma, const float* __restrict__ beta,
        const u16* __restrict__ X, float* __restrict__ Y, float inv_n) {
    __shared__ float rS[256], rQ[256];
    __shared__ float ssc[128], ssh[128];
    int tid = threadIdx.x;
    int c = tid & 127, half = tid >> 7;
    float s = 0.f, q = 0.f;
    for (int b = half; b < MBLKS; b += 2) {
        s += psum[b * 128 + c];
        q += psq [b * 128 + c];
    }
    rS[tid] = s; rQ[tid] = q;
    __syncthreads();
    if (tid < 128) {
        float S = rS[tid] + rS[tid + 128];
        float Q = rQ[tid] + rQ[tid + 128];
        float m = S * inv_n;
        float var = Q * inv_n - m * m;
        float rs = rsqrtf(var + 1e-5f);
        float sc = gamma[tid] * rs;
        ssc[tid] = sc;
        ssh[tid] = beta[tid] - sc * m;
    }
    __syncthreads();
    // apply to rows [blockIdx.x*256, +256): 16 groups-of-8 per row
    int g0 = blockIdx.x * 256 * 16;
#pragma unroll
    for (int it = 0; it < 16; ++it) {
        int g = g0 + it * 256 + tid;
        int row = g >> 4;
        if (row >= N_NODES) break;
        int col = (g & 15) << 3;
        float4 raw = ((const float4*)X)[g];
        const u16* xb = (const u16*)&raw;
        float4 y0, y1;
        y0.x = fmaxf(0.f, bf2f(xb[0]) * ssc[col + 0] + ssh[col + 0]);
        y0.y = fmaxf(0.f, bf2f(xb[1]) * ssc[col + 1] + ssh[col + 1]);
        y0.z = fmaxf(0.f, bf2f(xb[2]) * ssc[col + 2] + ssh[col + 2]);
        y0.w = fmaxf(0.f, bf2f(xb[3]) * ssc[col + 3] + ssh[col + 3]);
        y1.x = fmaxf(0.f, bf2f(xb[4]) * ssc[col + 4] + ssh[col + 4]);
        y1.y = fmaxf(0.f, bf2f(xb[5]) * ssc[col + 5] + ssh[col + 5]);
        y1.z = fmaxf(0.f, bf2f(xb[6]) * ssc[col + 6] + ssh[col + 6]);
        y1.w = fmaxf(0.f, bf2f(xb[7]) * ssc[col + 7] + ssh[col + 7]);
        ((float4*)Y)[g * 2]     = y0;
        ((float4*)Y)[g * 2 + 1] = y1;
    }
}

extern "C" void kernel_launch(void* const* d_in, const int* in_sizes, int n_in,
                              void* d_out, int out_size, void* d_ws, size_t ws_size,
                              hipStream_t stream) {
    const float* v    = (const float*)d_in[0];
    const int* src    = (const int*)d_in[1];
    const int* dst    = (const int*)d_in[2];
    const float* ew   = (const float*)d_in[3];
    const float* eps  = (const float*)d_in[4];
    const float* W1   = (const float*)d_in[5];
    const float* b1   = (const float*)d_in[6];
    const float* g1   = (const float*)d_in[7];
    const float* be1  = (const float*)d_in[8];
    const float* W2   = (const float*)d_in[9];
    const float* b2   = (const float*)d_in[10];
    const float* g2   = (const float*)d_in[11];
    const float* be2  = (const float*)d_in[12];
    float* out = (float*)d_out;

    // ---- workspace layout (bytes) ----
    char* base = (char*)d_ws;
    u16* x1   = (u16*)(base);                      // [N,512] bf16
    u16* vbf  = (u16*)(base + 51200000ull);        // [N,128] bf16
    u16* vagg = (u16*)(base + 64000000ull);        // [N,128] bf16
    u16* x2   = (u16*)(base + 76800000ull);        // [N,128] bf16 raw pre-BN2
    u16* W1t  = (u16*)(base + 89600000ull);        // 512x128 bf16
    u16* W2t  = (u16*)(base + 89731072ull);        // 128x512 bf16
    float* psum   = (float*)(base + 89862144ull);  // [196][512] fp32 max
    float* psq    = (float*)(base + 90663168ull);  // [196][512] fp32 max
    float* scale1 = (float*)(base + 91464192ull);  // 512
    float* shift1 = scale1 + 512;
    float* scale2 = shift1 + 512;                  // (unused slots kept for layout stability)
    float* shift2 = scale2 + 128;
    int* counts     = (int*)(shift2 + 128);        // 50,000
    int* row_start  = counts + 50000;              // 50,001 (+pad 3)
    int* pos        = row_start + 50004;           // 800,000
    int2* csr_ew    = (int2*)(pos + 800000);       // 800,000 * 8 B
    int* block_sums = (int*)(csr_ew + 800000);     // 256

    hipMemsetAsync(counts, 0, (size_t)50000 * sizeof(int), stream);

    // merged prep: cast | hist+pos | weight transpose
    prep_kernel<<<NB_CAST + NB_HIST + NB_W, 256, 0, stream>>>(v, vbf, dst, counts, pos,
                                                              W1, W2, W1t, W2t);
    reduce_kernel<<<SCAN_NB, 256, 0, stream>>>(counts, block_sums);
    scan_final<<<SCAN_NB, 256, 0, stream>>>(counts, block_sums, row_start);
    fill_kernel<<<NB_HIST, 256, 0, stream>>>(src, dst, ew, pos, row_start, csr_ew);
    gather_kernel<<<(N_NODES + 15) / 16, 256, 0, stream>>>(vbf, row_start, csr_ew, eps, vagg);

    // GEMM1: x1 = vagg @ W1 + b1 (bf16 raw) + BN1 partials — 256x128 tile
    {
        dim3 grid(D_HIDF / 128, MBLKS);
        mfma_gemm_bn<256, 128, 0><<<grid, 512, 0, stream>>>(vagg, W1t, b1, nullptr, nullptr,
                                                            x1, psum, psq, N_NODES, D_HIDF, D_INF);
    }
    bn_finalize_kernel<<<D_HIDF / 64, dim3(64, 16), 0, stream>>>(
        psum, psq, g1, be1, scale1, shift1, MBLKS, D_HIDF, 1.0f / N_NODES);

    // GEMM2: x2 = relu(bn1(x1)) @ W2 + b2 (bf16 raw) + BN2 partials — 256x64 tile
    {
        dim3 grid(D_OUTF / 64, MBLKS);
        mfma_gemm_bn<256, 64, 1><<<grid, 512, 0, stream>>>(x1, W2t, b2, scale1, shift1,
                                                           x2, psum, psq, N_NODES, D_OUTF, D_HIDF);
    }
    // BN2 finalize+apply fused: x2 (bf16) -> d_out (fp32)
    bn2_fused_kernel<<<SCAN_NB, 256, 0, stream>>>(psum, psq, g2, be2, x2, out, 1.0f / N_NODES);
}

// Round 12
// 307.907 us; speedup vs baseline: 1.0155x; 1.0155x over previous
//
#include <hip/hip_runtime.h>

#define N_NODES 50000
#define E_EDGES 800000
#define D_INF   128
#define D_HIDF  512
#define D_OUTF  128
#define SCAN_NB ((N_NODES + 255) / 256)   // 196 blocks
#define MBLKS   ((N_NODES + 255) / 256)   // 196 row-blocks per GEMM (256-row tiles)
#define EQ      (E_EDGES / 4)             // 200,000 edges per ILP slot

typedef unsigned short u16;
typedef __attribute__((ext_vector_type(8))) short short8;
typedef __attribute__((ext_vector_type(4))) float floatx4;

__device__ __forceinline__ u16 f2bf(float f) {
    union { float f; unsigned u; } v; v.f = f;
    unsigned r = (v.u + 0x7fffu + ((v.u >> 16) & 1u)) >> 16;
    return (u16)r;
}
__device__ __forceinline__ float bf2f(u16 b) {
    union { unsigned u; float f; } v; v.u = ((unsigned)b) << 16; return v.f;
}

// ---------------- cast v -> bf16 ----------------
__global__ void cast_v_kernel(const float* __restrict__ v, u16* __restrict__ vbf) {
    int i = blockIdx.x * blockDim.x + threadIdx.x;
    if (i >= N_NODES * D_INF / 8) return;
    const float4 a = ((const float4*)v)[i * 2];
    const float4 b = ((const float4*)v)[i * 2 + 1];
    u16 o[8];
    o[0] = f2bf(a.x); o[1] = f2bf(a.y); o[2] = f2bf(a.z); o[3] = f2bf(a.w);
    o[4] = f2bf(b.x); o[5] = f2bf(b.y); o[6] = f2bf(b.z); o[7] = f2bf(b.w);
    ((float4*)vbf)[i] = *(const float4*)o;
}

// ---------------- hist + per-edge pos: 4 independent returning atomics per thread ----------
__global__ void hist_kernel(const int* __restrict__ dst, int* __restrict__ counts,
                            int* __restrict__ pos) {
    int t = blockIdx.x * blockDim.x + threadIdx.x;
    if (t >= EQ) return;
    int d0 = dst[t];
    int d1 = dst[t + EQ];
    int d2 = dst[t + 2 * EQ];
    int d3 = dst[t + 3 * EQ];
    int p0 = atomicAdd(&counts[d0], 1);
    int p1 = atomicAdd(&counts[d1], 1);
    int p2 = atomicAdd(&counts[d2], 1);
    int p3 = atomicAdd(&counts[d3], 1);
    pos[t]          = p0;
    pos[t + EQ]     = p1;
    pos[t + 2 * EQ] = p2;
    pos[t + 3 * EQ] = p3;
}

// ---------------- weight prep ----------------
__global__ void prep_weights_kernel(const float* __restrict__ W1, const float* __restrict__ W2,
                                    u16* __restrict__ W1t, u16* __restrict__ W2t) {
    int idx = blockIdx.x * blockDim.x + threadIdx.x;
    if (idx >= 128 * 512) return;
    int k1 = idx >> 9, n1 = idx & 511;      // W1 [128][512]
    W1t[n1 * 128 + k1] = f2bf(W1[idx]);
    int k2 = idx >> 7, n2 = idx & 127;      // W2 [512][128]
    W2t[n2 * 512 + k2] = f2bf(W2[idx]);
}

// ---------------- scan phase 1: per-block sums ----------------
__global__ __launch_bounds__(256) void reduce_kernel(const int* __restrict__ counts,
                                                     int* __restrict__ block_sums) {
    __shared__ int lsum[4];
    int tid = threadIdx.x;
    int gid = blockIdx.x * 256 + tid;
    int s = (gid < N_NODES) ? counts[gid] : 0;
#pragma unroll
    for (int off = 32; off; off >>= 1) s += __shfl_down(s, off);
    if ((tid & 63) == 0) lsum[tid >> 6] = s;
    __syncthreads();
    if (tid == 0) block_sums[blockIdx.x] = lsum[0] + lsum[1] + lsum[2] + lsum[3];
}

// ---------------- scan phase 2 (merged): local scan + redundant block-sum scan ----------------
__global__ __launch_bounds__(256) void scan_final(const int* __restrict__ counts,
                                                  const int* __restrict__ block_sums,
                                                  int* __restrict__ row_start) {
    __shared__ int sh[256];
    __shared__ int bs[256];
    int tid = threadIdx.x;
    int gid = blockIdx.x * 256 + tid;
    sh[tid] = (gid < N_NODES) ? counts[gid] : 0;
    bs[tid] = (tid < SCAN_NB) ? block_sums[tid] : 0;
    __syncthreads();
    for (int off = 1; off < 256; off <<= 1) {
        int t1 = (tid >= off) ? sh[tid - off] : 0;
        int t2 = (tid >= off) ? bs[tid - off] : 0;
        __syncthreads();
        sh[tid] += t1;
        bs[tid] += t2;
        __syncthreads();
    }
    int boff = (blockIdx.x == 0) ? 0 : bs[blockIdx.x - 1];
    int excl = (tid == 0) ? 0 : sh[tid - 1];
    if (gid < N_NODES) row_start[gid] = boff + excl;
    if (gid == 0) row_start[N_NODES] = E_EDGES;
}

// ---------------- CSR fill — no atomics ----------------
__global__ void fill_kernel(const int* __restrict__ src, const int* __restrict__ dst,
                            const float* __restrict__ w, const int* __restrict__ pos,
                            const int* __restrict__ row_start,
                            int2* __restrict__ csr_ew) {
    int e = blockIdx.x * blockDim.x + threadIdx.x;
    if (e >= E_EDGES) return;
    int d = dst[e];
    int idx = row_start[d] + pos[e];
    int2 rec;
    rec.x = src[e];
    rec.y = __float_as_int(w[e]);
    csr_ew[idx] = rec;
}

// ---------------- gather: 16 lanes/node, ushort8 (16B) per lane, 2-edge unroll ----------
__global__ __launch_bounds__(256) void gather_kernel(const u16* __restrict__ vbf,
                                                     const int* __restrict__ row_start,
                                                     const int2* __restrict__ csr_ew,
                                                     const float* __restrict__ eps_p,
                                                     u16* __restrict__ vagg) {
    int node = blockIdx.x * 16 + (threadIdx.x >> 4);
    if (node >= N_NODES) return;
    int c8 = (threadIdx.x & 15) << 3;
    int beg = row_start[node];
    int end = row_start[node + 1];
    float a[8] = {};
    int j = beg;
    for (; j + 1 < end; j += 2) {
        int2 e0 = csr_ew[j];
        int2 e1 = csr_ew[j + 1];
        float w0 = __int_as_float(e0.y);
        float w1 = __int_as_float(e1.y);
        float4 r0 = *(const float4*)(vbf + (size_t)e0.x * D_INF + c8);
        float4 r1 = *(const float4*)(vbf + (size_t)e1.x * D_INF + c8);
        const u16* p0 = (const u16*)&r0;
        const u16* p1 = (const u16*)&r1;
#pragma unroll
        for (int t = 0; t < 8; ++t) a[t] += w0 * bf2f(p0[t]);
#pragma unroll
        for (int t = 0; t < 8; ++t) a[t] += w1 * bf2f(p1[t]);
    }
    if (j < end) {
        int2 e0 = csr_ew[j];
        float w0 = __int_as_float(e0.y);
        float4 r0 = *(const float4*)(vbf + (size_t)e0.x * D_INF + c8);
        const u16* p0 = (const u16*)&r0;
#pragma unroll
        for (int t = 0; t < 8; ++t) a[t] += w0 * bf2f(p0[t]);
    }
    float e = eps_p[0];
    float4 rn = *(const float4*)(vbf + (size_t)node * D_INF + c8);
    const u16* pn = (const u16*)&rn;
    u16 o[8];
#pragma unroll
    for (int t = 0; t < 8; ++t) o[t] = f2bf(a[t] + e * bf2f(pn[t]));
    *(float4*)(vagg + (size_t)node * D_INF + c8) = *(const float4*)o;
}

// ---------------- MFMA GEMM + bias + per-block BN partials, LDS-coalesced bf16 out ----------
template<int MT, int NT, int FUSE_A_BN>
__global__ __launch_bounds__(512) void mfma_gemm_bn(
        const u16* __restrict__ A, const u16* __restrict__ Bt,
        const float* __restrict__ bias,
        const float* __restrict__ a_scale, const float* __restrict__ a_shift,
        u16* __restrict__ Cout,
        float* __restrict__ psum, float* __restrict__ psq,
        int M, int Ncols, int K) {
    constexpr int NJ = NT / 32;
    constexpr int STG = (MT + NT) * 96;
    constexpr int SMEM_BYTES = (STG > 34816) ? STG : 34816;
    __shared__ __align__(16) char smem_raw[SMEM_BYTES];
    u16* As = (u16*)smem_raw;
    u16* Bs = As + MT * 48;
    const int bm = blockIdx.y * MT;
    const int bn = blockIdx.x * NT;
    const int tid = threadIdx.x;
    const int wave = tid >> 6, lane = tid & 63;
    const int wr = wave >> 1, wc = wave & 1;
    const int wm = wr * 64;
    const int wn = wc * (NT / 2);
    const int lm = lane & 15, quad = lane >> 4;

    floatx4 acc[4][NJ] = {};

    const int ksteps = K >> 5;
    for (int ks = 0; ks < ksteps; ++ks) {
        const int k0 = ks << 5;
        for (int c = tid; c < (MT + NT) * 4; c += 512) {
            int r = c >> 2;
            int kk = (c & 3) << 3;
            if (r < MT) {
                int row = bm + r;
                float4 av = make_float4(0.f, 0.f, 0.f, 0.f);
                if (row < M) {
                    av = *(const float4*)(A + (size_t)row * K + k0 + kk);
                    if (FUSE_A_BN) {
                        u16* ab = (u16*)&av;
                        const float4 s0 = *(const float4*)(a_scale + k0 + kk);
                        const float4 s1 = *(const float4*)(a_scale + k0 + kk + 4);
                        const float4 h0 = *(const float4*)(a_shift + k0 + kk);
                        const float4 h1 = *(const float4*)(a_shift + k0 + kk + 4);
                        ab[0] = f2bf(fmaxf(0.f, bf2f(ab[0]) * s0.x + h0.x));
                        ab[1] = f2bf(fmaxf(0.f, bf2f(ab[1]) * s0.y + h0.y));
                        ab[2] = f2bf(fmaxf(0.f, bf2f(ab[2]) * s0.z + h0.z));
                        ab[3] = f2bf(fmaxf(0.f, bf2f(ab[3]) * s0.w + h0.w));
                        ab[4] = f2bf(fmaxf(0.f, bf2f(ab[4]) * s1.x + h1.x));
                        ab[5] = f2bf(fmaxf(0.f, bf2f(ab[5]) * s1.y + h1.y));
                        ab[6] = f2bf(fmaxf(0.f, bf2f(ab[6]) * s1.z + h1.z));
                        ab[7] = f2bf(fmaxf(0.f, bf2f(ab[7]) * s1.w + h1.w));
                    }
                }
                *(float4*)&As[r * 48 + kk] = av;
            } else {
                int rb = r - MT;
                *(float4*)&Bs[rb * 48 + kk] =
                    *(const float4*)(Bt + (size_t)(bn + rb) * K + k0 + kk);
            }
        }
        __syncthreads();
        short8 af[4], bfr[NJ];
#pragma unroll
        for (int i = 0; i < 4; ++i)
            af[i] = *(const short8*)&As[(wm + i * 16 + lm) * 48 + quad * 8];
#pragma unroll
        for (int j = 0; j < NJ; ++j)
            bfr[j] = *(const short8*)&Bs[(wn + j * 16 + lm) * 48 + quad * 8];
#pragma unroll
        for (int i = 0; i < 4; ++i)
#pragma unroll
            for (int j = 0; j < NJ; ++j)
                acc[i][j] = __builtin_amdgcn_mfma_f32_16x16x32_bf16(af[i], bfr[j], acc[i][j], 0, 0, 0);
        __syncthreads();
    }

    // ---- per-block BN partials ----
    float* redS = (float*)smem_raw;
    float* redQ = redS + NT;
    if (tid < NT) { redS[tid] = 0.f; redQ[tid] = 0.f; }
    __syncthreads();
    float bjv[NJ];
#pragma unroll
    for (int j = 0; j < NJ; ++j) {
        int cl = wn + j * 16 + lm;
        bjv[j] = bias[bn + cl];
        float s = 0.f, q = 0.f;
#pragma unroll
        for (int i = 0; i < 4; ++i) {
            int row0 = bm + wm + i * 16 + quad * 4;
#pragma unroll
            for (int r = 0; r < 4; ++r) {
                if (row0 + r < M) {
                    float x = acc[i][j][r] + bjv[j];
                    s += x; q += x * x;
                }
            }
        }
        s += __shfl_xor(s, 16); q += __shfl_xor(q, 16);
        s += __shfl_xor(s, 32); q += __shfl_xor(q, 32);
        if (quad == 0) {
            atomicAdd(&redS[cl], s);
            atomicAdd(&redQ[cl], q);
        }
    }
    __syncthreads();
    if (tid < NT) {
        psum[(size_t)blockIdx.y * Ncols + bn + tid] = redS[tid];
        psq [(size_t)blockIdx.y * Ncols + bn + tid] = redQ[tid];
    }

    // ---- coalesced bf16 output via LDS obuf: passes of 128 rows x 64 cols ----
    float* obuf = (float*)smem_raw;
    constexpr int RH = MT / 128;
    constexpr int JH = NT / 64;
#pragma unroll
    for (int rh = 0; rh < RH; ++rh) {
#pragma unroll
        for (int jh = 0; jh < (JH ? JH : 1); ++jh) {
            __syncthreads();
            bool part = ((wr >> 1) == rh) && (NT == 64 || wc == jh);
            if (part) {
                int rbase = wm - rh * 128;
#pragma unroll
                for (int i = 0; i < 4; ++i)
#pragma unroll
                    for (int j = 0; j < NJ; ++j) {
                        int cp = (NT == 128) ? (j * 16 + lm) : (wn + j * 16 + lm);
#pragma unroll
                        for (int r = 0; r < 4; ++r)
                            obuf[(rbase + i * 16 + quad * 4 + r) * 68 + cp] =
                                acc[i][j][r] + bjv[j];
                    }
            }
            __syncthreads();
            int lr = tid >> 2;
            int seg = (tid & 3) << 4;
            int grow = bm + rh * 128 + lr;
            if (grow < M) {
                u16 ob[16];
#pragma unroll
                for (int t = 0; t < 4; ++t) {
                    float4 f = *(float4*)&obuf[lr * 68 + seg + t * 4];
                    ob[t * 4 + 0] = f2bf(f.x);
                    ob[t * 4 + 1] = f2bf(f.y);
                    ob[t * 4 + 2] = f2bf(f.z);
                    ob[t * 4 + 3] = f2bf(f.w);
                }
                u16* dstp = Cout + (size_t)grow * Ncols + bn + jh * 64 + seg;
                *(float4*)dstp       = *(float4*)(ob);
                *(float4*)(dstp + 8) = *(float4*)(ob + 8);
            }
        }
    }
}

// ---------------- BN1 finalize (parallel) ----------------
__global__ __launch_bounds__(1024) void bn_finalize_kernel(
        const float* __restrict__ psum, const float* __restrict__ psq,
        const float* __restrict__ gamma, const float* __restrict__ beta,
        float* __restrict__ scale, float* __restrict__ shift,
        int nblocks, int Ncols, float inv_n) {
    __shared__ float shS[16][64];
    __shared__ float shQ[16][64];
    const int tx = threadIdx.x;
    const int ty = threadIdx.y;
    const int c = blockIdx.x * 64 + tx;
    float s = 0.f, q = 0.f;
    for (int b = ty; b < nblocks; b += 16) {
        s += psum[(size_t)b * Ncols + c];
        q += psq [(size_t)b * Ncols + c];
    }
    shS[ty][tx] = s;
    shQ[ty][tx] = q;
    __syncthreads();
    if (ty == 0) {
        float S = 0.f, Q = 0.f;
#pragma unroll
        for (int r = 0; r < 16; ++r) { S += shS[r][tx]; Q += shQ[r][tx]; }
        float m = S * inv_n;
        float var = Q * inv_n - m * m;
        float rs = rsqrtf(var + 1e-5f);
        float sc = gamma[c] * rs;
        scale[c] = sc;
        shift[c] = beta[c] - sc * m;
    }
}

// ---------------- BN2 fused finalize+apply ----------------
__global__ __launch_bounds__(256) void bn2_fused_kernel(
        const float* __restrict__ psum, const float* __restrict__ psq,
        const float* __restrict__ gamma, const float* __restrict__ beta,
        const u16* __restrict__ X, float* __restrict__ Y, float inv_n) {
    __shared__ float rS[256], rQ[256];
    __shared__ float ssc[128], ssh[128];
    int tid = threadIdx.x;
    int c = tid & 127, half = tid >> 7;
    float s = 0.f, q = 0.f;
    for (int b = half; b < MBLKS; b += 2) {
        s += psum[b * 128 + c];
        q += psq [b * 128 + c];
    }
    rS[tid] = s; rQ[tid] = q;
    __syncthreads();
    if (tid < 128) {
        float S = rS[tid] + rS[tid + 128];
        float Q = rQ[tid] + rQ[tid + 128];
        float m = S * inv_n;
        float var = Q * inv_n - m * m;
        float rs = rsqrtf(var + 1e-5f);
        float sc = gamma[tid] * rs;
        ssc[tid] = sc;
        ssh[tid] = beta[tid] - sc * m;
    }
    __syncthreads();
    int g0 = blockIdx.x * 256 * 16;
#pragma unroll
    for (int it = 0; it < 16; ++it) {
        int g = g0 + it * 256 + tid;
        int row = g >> 4;
        if (row >= N_NODES) break;
        int col = (g & 15) << 3;
        float4 raw = ((const float4*)X)[g];
        const u16* xb = (const u16*)&raw;
        float4 y0, y1;
        y0.x = fmaxf(0.f, bf2f(xb[0]) * ssc[col + 0] + ssh[col + 0]);
        y0.y = fmaxf(0.f, bf2f(xb[1]) * ssc[col + 1] + ssh[col + 1]);
        y0.z = fmaxf(0.f, bf2f(xb[2]) * ssc[col + 2] + ssh[col + 2]);
        y0.w = fmaxf(0.f, bf2f(xb[3]) * ssc[col + 3] + ssh[col + 3]);
        y1.x = fmaxf(0.f, bf2f(xb[4]) * ssc[col + 4] + ssh[col + 4]);
        y1.y = fmaxf(0.f, bf2f(xb[5]) * ssc[col + 5] + ssh[col + 5]);
        y1.z = fmaxf(0.f, bf2f(xb[6]) * ssc[col + 6] + ssh[col + 6]);
        y1.w = fmaxf(0.f, bf2f(xb[7]) * ssc[col + 7] + ssh[col + 7]);
        ((float4*)Y)[g * 2]     = y0;
        ((float4*)Y)[g * 2 + 1] = y1;
    }
}

extern "C" void kernel_launch(void* const* d_in, const int* in_sizes, int n_in,
                              void* d_out, int out_size, void* d_ws, size_t ws_size,
                              hipStream_t stream) {
    const float* v    = (const float*)d_in[0];
    const int* src    = (const int*)d_in[1];
    const int* dst    = (const int*)d_in[2];
    const float* ew   = (const float*)d_in[3];
    const float* eps  = (const float*)d_in[4];
    const float* W1   = (const float*)d_in[5];
    const float* b1   = (const float*)d_in[6];
    const float* g1   = (const float*)d_in[7];
    const float* be1  = (const float*)d_in[8];
    const float* W2   = (const float*)d_in[9];
    const float* b2   = (const float*)d_in[10];
    const float* g2   = (const float*)d_in[11];
    const float* be2  = (const float*)d_in[12];
    float* out = (float*)d_out;

    // ---- workspace layout (bytes) ----
    char* base = (char*)d_ws;
    u16* x1   = (u16*)(base);                      // [N,512] bf16
    u16* vbf  = (u16*)(base + 51200000ull);        // [N,128] bf16
    u16* vagg = (u16*)(base + 64000000ull);        // [N,128] bf16
    u16* x2   = (u16*)(base + 76800000ull);        // [N,128] bf16 raw pre-BN2
    u16* W1t  = (u16*)(base + 89600000ull);        // 512x128 bf16
    u16* W2t  = (u16*)(base + 89731072ull);        // 128x512 bf16
    float* psum   = (float*)(base + 89862144ull);  // [196][512] fp32 max
    float* psq    = (float*)(base + 90663168ull);  // [196][512] fp32 max
    float* scale1 = (float*)(base + 91464192ull);  // 512
    float* shift1 = scale1 + 512;
    float* scale2 = shift1 + 512;
    float* shift2 = scale2 + 128;
    int* counts     = (int*)(shift2 + 128);        // 50,000
    int* row_start  = counts + 50000;              // 50,001 (+pad 3)
    int* pos        = row_start + 50004;           // 800,000
    int2* csr_ew    = (int2*)(pos + 800000);       // 800,000 * 8 B
    int* block_sums = (int*)(csr_ew + 800000);     // 256

    hipMemsetAsync(counts, 0, (size_t)50000 * sizeof(int), stream);

    // CSR build + casts (separate dispatches; hist has 4-edge ILP)
    cast_v_kernel<<<(N_NODES * D_INF / 8 + 255) / 256, 256, 0, stream>>>(v, vbf);
    hist_kernel<<<(EQ + 255) / 256, 256, 0, stream>>>(dst, counts, pos);
    prep_weights_kernel<<<(128 * 512 + 255) / 256, 256, 0, stream>>>(W1, W2, W1t, W2t);
    reduce_kernel<<<SCAN_NB, 256, 0, stream>>>(counts, block_sums);
    scan_final<<<SCAN_NB, 256, 0, stream>>>(counts, block_sums, row_start);
    fill_kernel<<<(E_EDGES + 255) / 256, 256, 0, stream>>>(src, dst, ew, pos, row_start, csr_ew);
    gather_kernel<<<(N_NODES + 15) / 16, 256, 0, stream>>>(vbf, row_start, csr_ew, eps, vagg);

    // GEMM1: x1 = vagg @ W1 + b1 (bf16 raw) + BN1 partials — 256x128 tile
    {
        dim3 grid(D_HIDF / 128, MBLKS);
        mfma_gemm_bn<256, 128, 0><<<grid, 512, 0, stream>>>(vagg, W1t, b1, nullptr, nullptr,
                                                            x1, psum, psq, N_NODES, D_HIDF, D_INF);
    }
    bn_finalize_kernel<<<D_HIDF / 64, dim3(64, 16), 0, stream>>>(
        psum, psq, g1, be1, scale1, shift1, MBLKS, D_HIDF, 1.0f / N_NODES);

    // GEMM2: x2 = relu(bn1(x1)) @ W2 + b2 (bf16 raw) + BN2 partials — 256x64 tile
    {
        dim3 grid(D_OUTF / 64, MBLKS);
        mfma_gemm_bn<256, 64, 1><<<grid, 512, 0, stream>>>(x1, W2t, b2, scale1, shift1,
                                                           x2, psum, psq, N_NODES, D_OUTF, D_HIDF);
    }
    // BN2 finalize+apply fused: x2 (bf16) -> d_out (fp32)
    bn2_fused_kernel<<<SCAN_NB, 256, 0, stream>>>(psum, psq, g2, be2, x2, out, 1.0f / N_NODES);
}

// Round 13
// 282.163 us; speedup vs baseline: 1.1081x; 1.0912x over previous
//
#include <hip/hip_runtime.h>

#define N_NODES 50000
#define E_EDGES 800000
#define D_INF   128
#define D_HIDF  512
#define D_OUTF  128
#define SCAN_NB ((N_NODES + 255) / 256)   // 196 blocks
#define MBLKS   ((N_NODES + 255) / 256)   // 196 row-blocks per GEMM (256-row tiles)
#define EQ      (E_EDGES / 4)             // 200,000 edges per ILP slot

typedef unsigned short u16;
typedef __attribute__((ext_vector_type(8))) short short8;
typedef __attribute__((ext_vector_type(4))) float floatx4;

__device__ __forceinline__ u16 f2bf(float f) {
    union { float f; unsigned u; } v; v.f = f;
    unsigned r = (v.u + 0x7fffu + ((v.u >> 16) & 1u)) >> 16;
    return (u16)r;
}
__device__ __forceinline__ float bf2f(u16 b) {
    union { unsigned u; float f; } v; v.u = ((unsigned)b) << 16; return v.f;
}

// ---------------- cast v -> bf16 ----------------
__global__ void cast_v_kernel(const float* __restrict__ v, u16* __restrict__ vbf) {
    int i = blockIdx.x * blockDim.x + threadIdx.x;
    if (i >= N_NODES * D_INF / 8) return;
    const float4 a = ((const float4*)v)[i * 2];
    const float4 b = ((const float4*)v)[i * 2 + 1];
    u16 o[8];
    o[0] = f2bf(a.x); o[1] = f2bf(a.y); o[2] = f2bf(a.z); o[3] = f2bf(a.w);
    o[4] = f2bf(b.x); o[5] = f2bf(b.y); o[6] = f2bf(b.z); o[7] = f2bf(b.w);
    ((float4*)vbf)[i] = *(const float4*)o;
}

// ---------------- hist + per-edge pos: 4 independent returning atomics per thread ----------
__global__ void hist_kernel(const int* __restrict__ dst, int* __restrict__ counts,
                            int* __restrict__ pos) {
    int t = blockIdx.x * blockDim.x + threadIdx.x;
    if (t >= EQ) return;
    int d0 = dst[t];
    int d1 = dst[t + EQ];
    int d2 = dst[t + 2 * EQ];
    int d3 = dst[t + 3 * EQ];
    int p0 = atomicAdd(&counts[d0], 1);
    int p1 = atomicAdd(&counts[d1], 1);
    int p2 = atomicAdd(&counts[d2], 1);
    int p3 = atomicAdd(&counts[d3], 1);
    pos[t]          = p0;
    pos[t + EQ]     = p1;
    pos[t + 2 * EQ] = p2;
    pos[t + 3 * EQ] = p3;
}

// ---------------- weight prep ----------------
__global__ void prep_weights_kernel(const float* __restrict__ W1, const float* __restrict__ W2,
                                    u16* __restrict__ W1t, u16* __restrict__ W2t) {
    int idx = blockIdx.x * blockDim.x + threadIdx.x;
    if (idx >= 128 * 512) return;
    int k1 = idx >> 9, n1 = idx & 511;      // W1 [128][512]
    W1t[n1 * 128 + k1] = f2bf(W1[idx]);
    int k2 = idx >> 7, n2 = idx & 127;      // W2 [512][128]
    W2t[n2 * 512 + k2] = f2bf(W2[idx]);
}

// ---------------- scan phase 1: per-block sums ----------------
__global__ __launch_bounds__(256) void reduce_kernel(const int* __restrict__ counts,
                                                     int* __restrict__ block_sums) {
    __shared__ int lsum[4];
    int tid = threadIdx.x;
    int gid = blockIdx.x * 256 + tid;
    int s = (gid < N_NODES) ? counts[gid] : 0;
#pragma unroll
    for (int off = 32; off; off >>= 1) s += __shfl_down(s, off);
    if ((tid & 63) == 0) lsum[tid >> 6] = s;
    __syncthreads();
    if (tid == 0) block_sums[blockIdx.x] = lsum[0] + lsum[1] + lsum[2] + lsum[3];
}

// ---------------- scan phase 2 (merged): local scan + redundant block-sum scan ----------------
__global__ __launch_bounds__(256) void scan_final(const int* __restrict__ counts,
                                                  const int* __restrict__ block_sums,
                                                  int* __restrict__ row_start) {
    __shared__ int sh[256];
    __shared__ int bs[256];
    int tid = threadIdx.x;
    int gid = blockIdx.x * 256 + tid;
    sh[tid] = (gid < N_NODES) ? counts[gid] : 0;
    bs[tid] = (tid < SCAN_NB) ? block_sums[tid] : 0;
    __syncthreads();
    for (int off = 1; off < 256; off <<= 1) {
        int t1 = (tid >= off) ? sh[tid - off] : 0;
        int t2 = (tid >= off) ? bs[tid - off] : 0;
        __syncthreads();
        sh[tid] += t1;
        bs[tid] += t2;
        __syncthreads();
    }
    int boff = (blockIdx.x == 0) ? 0 : bs[blockIdx.x - 1];
    int excl = (tid == 0) ? 0 : sh[tid - 1];
    if (gid < N_NODES) row_start[gid] = boff + excl;
    if (gid == 0) row_start[N_NODES] = E_EDGES;
}

// ---------------- CSR fill — no atomics ----------------
__global__ void fill_kernel(const int* __restrict__ src, const int* __restrict__ dst,
                            const float* __restrict__ w, const int* __restrict__ pos,
                            const int* __restrict__ row_start,
                            int2* __restrict__ csr_ew) {
    int e = blockIdx.x * blockDim.x + threadIdx.x;
    if (e >= E_EDGES) return;
    int d = dst[e];
    int idx = row_start[d] + pos[e];
    int2 rec;
    rec.x = src[e];
    rec.y = __float_as_int(w[e]);
    csr_ew[idx] = rec;
}

// ---------------- gather: 16 lanes/node, ushort8 (16B) per lane, 2-edge unroll ----------
__global__ __launch_bounds__(256) void gather_kernel(const u16* __restrict__ vbf,
                                                     const int* __restrict__ row_start,
                                                     const int2* __restrict__ csr_ew,
                                                     const float* __restrict__ eps_p,
                                                     u16* __restrict__ vagg) {
    int node = blockIdx.x * 16 + (threadIdx.x >> 4);
    if (node >= N_NODES) return;
    int c8 = (threadIdx.x & 15) << 3;
    int beg = row_start[node];
    int end = row_start[node + 1];
    float a[8] = {};
    int j = beg;
    for (; j + 1 < end; j += 2) {
        int2 e0 = csr_ew[j];
        int2 e1 = csr_ew[j + 1];
        float w0 = __int_as_float(e0.y);
        float w1 = __int_as_float(e1.y);
        float4 r0 = *(const float4*)(vbf + (size_t)e0.x * D_INF + c8);
        float4 r1 = *(const float4*)(vbf + (size_t)e1.x * D_INF + c8);
        const u16* p0 = (const u16*)&r0;
        const u16* p1 = (const u16*)&r1;
#pragma unroll
        for (int t = 0; t < 8; ++t) a[t] += w0 * bf2f(p0[t]);
#pragma unroll
        for (int t = 0; t < 8; ++t) a[t] += w1 * bf2f(p1[t]);
    }
    if (j < end) {
        int2 e0 = csr_ew[j];
        float w0 = __int_as_float(e0.y);
        float4 r0 = *(const float4*)(vbf + (size_t)e0.x * D_INF + c8);
        const u16* p0 = (const u16*)&r0;
#pragma unroll
        for (int t = 0; t < 8; ++t) a[t] += w0 * bf2f(p0[t]);
    }
    float e = eps_p[0];
    float4 rn = *(const float4*)(vbf + (size_t)node * D_INF + c8);
    const u16* pn = (const u16*)&rn;
    u16 o[8];
#pragma unroll
    for (int t = 0; t < 8; ++t) o[t] = f2bf(a[t] + e * bf2f(pn[t]));
    *(float4*)(vagg + (size_t)node * D_INF + c8) = *(const float4*)o;
}

// ---------------- MFMA GEMM + bias + per-block BN partials, LDS-coalesced bf16 out ----------
template<int MT, int NT, int FUSE_A_BN>
__global__ __launch_bounds__(512) void mfma_gemm_bn(
        const u16* __restrict__ A, const u16* __restrict__ Bt,
        const float* __restrict__ bias,
        const float* __restrict__ a_scale, const float* __restrict__ a_shift,
        u16* __restrict__ Cout,
        float* __restrict__ psum, float* __restrict__ psq,
        int M, int Ncols, int K) {
    constexpr int NJ = NT / 32;
    constexpr int STG = (MT + NT) * 96;
    constexpr int SMEM_BYTES = (STG > 34816) ? STG : 34816;
    __shared__ __align__(16) char smem_raw[SMEM_BYTES];
    u16* As = (u16*)smem_raw;
    u16* Bs = As + MT * 48;
    const int bm = blockIdx.y * MT;
    const int bn = blockIdx.x * NT;
    const int tid = threadIdx.x;
    const int wave = tid >> 6, lane = tid & 63;
    const int wr = wave >> 1, wc = wave & 1;
    const int wm = wr * 64;
    const int wn = wc * (NT / 2);
    const int lm = lane & 15, quad = lane >> 4;

    floatx4 acc[4][NJ] = {};

    const int ksteps = K >> 5;
    for (int ks = 0; ks < ksteps; ++ks) {
        const int k0 = ks << 5;
        for (int c = tid; c < (MT + NT) * 4; c += 512) {
            int r = c >> 2;
            int kk = (c & 3) << 3;
            if (r < MT) {
                int row = bm + r;
                float4 av = make_float4(0.f, 0.f, 0.f, 0.f);
                if (row < M) {
                    av = *(const float4*)(A + (size_t)row * K + k0 + kk);
                    if (FUSE_A_BN) {
                        u16* ab = (u16*)&av;
                        const float4 s0 = *(const float4*)(a_scale + k0 + kk);
                        const float4 s1 = *(const float4*)(a_scale + k0 + kk + 4);
                        const float4 h0 = *(const float4*)(a_shift + k0 + kk);
                        const float4 h1 = *(const float4*)(a_shift + k0 + kk + 4);
                        ab[0] = f2bf(fmaxf(0.f, bf2f(ab[0]) * s0.x + h0.x));
                        ab[1] = f2bf(fmaxf(0.f, bf2f(ab[1]) * s0.y + h0.y));
                        ab[2] = f2bf(fmaxf(0.f, bf2f(ab[2]) * s0.z + h0.z));
                        ab[3] = f2bf(fmaxf(0.f, bf2f(ab[3]) * s0.w + h0.w));
                        ab[4] = f2bf(fmaxf(0.f, bf2f(ab[4]) * s1.x + h1.x));
                        ab[5] = f2bf(fmaxf(0.f, bf2f(ab[5]) * s1.y + h1.y));
                        ab[6] = f2bf(fmaxf(0.f, bf2f(ab[6]) * s1.z + h1.z));
                        ab[7] = f2bf(fmaxf(0.f, bf2f(ab[7]) * s1.w + h1.w));
                    }
                }
                *(float4*)&As[r * 48 + kk] = av;
            } else {
                int rb = r - MT;
                *(float4*)&Bs[rb * 48 + kk] =
                    *(const float4*)(Bt + (size_t)(bn + rb) * K + k0 + kk);
            }
        }
        __syncthreads();
        short8 af[4], bfr[NJ];
#pragma unroll
        for (int i = 0; i < 4; ++i)
            af[i] = *(const short8*)&As[(wm + i * 16 + lm) * 48 + quad * 8];
#pragma unroll
        for (int j = 0; j < NJ; ++j)
            bfr[j] = *(const short8*)&Bs[(wn + j * 16 + lm) * 48 + quad * 8];
#pragma unroll
        for (int i = 0; i < 4; ++i)
#pragma unroll
            for (int j = 0; j < NJ; ++j)
                acc[i][j] = __builtin_amdgcn_mfma_f32_16x16x32_bf16(af[i], bfr[j], acc[i][j], 0, 0, 0);
        __syncthreads();
    }

    // ---- per-block BN partials ----
    float* redS = (float*)smem_raw;
    float* redQ = redS + NT;
    if (tid < NT) { redS[tid] = 0.f; redQ[tid] = 0.f; }
    __syncthreads();
    float bjv[NJ];
#pragma unroll
    for (int j = 0; j < NJ; ++j) {
        int cl = wn + j * 16 + lm;
        bjv[j] = bias[bn + cl];
        float s = 0.f, q = 0.f;
#pragma unroll
        for (int i = 0; i < 4; ++i) {
            int row0 = bm + wm + i * 16 + quad * 4;
#pragma unroll
            for (int r = 0; r < 4; ++r) {
                if (row0 + r < M) {
                    float x = acc[i][j][r] + bjv[j];
                    s += x; q += x * x;
                }
            }
        }
        s += __shfl_xor(s, 16); q += __shfl_xor(q, 16);
        s += __shfl_xor(s, 32); q += __shfl_xor(q, 32);
        if (quad == 0) {
            atomicAdd(&redS[cl], s);
            atomicAdd(&redQ[cl], q);
        }
    }
    __syncthreads();
    if (tid < NT) {
        psum[(size_t)blockIdx.y * Ncols + bn + tid] = redS[tid];
        psq [(size_t)blockIdx.y * Ncols + bn + tid] = redQ[tid];
    }

    // ---- coalesced bf16 output via LDS obuf: passes of 128 rows x 64 cols ----
    float* obuf = (float*)smem_raw;
    constexpr int RH = MT / 128;
    constexpr int JH = NT / 64;
#pragma unroll
    for (int rh = 0; rh < RH; ++rh) {
#pragma unroll
        for (int jh = 0; jh < (JH ? JH : 1); ++jh) {
            __syncthreads();
            bool part = ((wr >> 1) == rh) && (NT == 64 || wc == jh);
            if (part) {
                int rbase = wm - rh * 128;
#pragma unroll
                for (int i = 0; i < 4; ++i)
#pragma unroll
                    for (int j = 0; j < NJ; ++j) {
                        int cp = (NT == 128) ? (j * 16 + lm) : (wn + j * 16 + lm);
#pragma unroll
                        for (int r = 0; r < 4; ++r)
                            obuf[(rbase + i * 16 + quad * 4 + r) * 68 + cp] =
                                acc[i][j][r] + bjv[j];
                    }
            }
            __syncthreads();
            int lr = tid >> 2;
            int seg = (tid & 3) << 4;
            int grow = bm + rh * 128 + lr;
            if (grow < M) {
                u16 ob[16];
#pragma unroll
                for (int t = 0; t < 4; ++t) {
                    float4 f = *(float4*)&obuf[lr * 68 + seg + t * 4];
                    ob[t * 4 + 0] = f2bf(f.x);
                    ob[t * 4 + 1] = f2bf(f.y);
                    ob[t * 4 + 2] = f2bf(f.z);
                    ob[t * 4 + 3] = f2bf(f.w);
                }
                u16* dstp = Cout + (size_t)grow * Ncols + bn + jh * 64 + seg;
                *(float4*)dstp       = *(float4*)(ob);
                *(float4*)(dstp + 8) = *(float4*)(ob + 8);
            }
        }
    }
}

// ---------------- BN finalize (parallel reduce of per-block partials) ----------------
__global__ __launch_bounds__(1024) void bn_finalize_kernel(
        const float* __restrict__ psum, const float* __restrict__ psq,
        const float* __restrict__ gamma, const float* __restrict__ beta,
        float* __restrict__ scale, float* __restrict__ shift,
        int nblocks, int Ncols, float inv_n) {
    __shared__ float shS[16][64];
    __shared__ float shQ[16][64];
    const int tx = threadIdx.x;
    const int ty = threadIdx.y;
    const int c = blockIdx.x * 64 + tx;
    float s = 0.f, q = 0.f;
    for (int b = ty; b < nblocks; b += 16) {
        s += psum[(size_t)b * Ncols + c];
        q += psq [(size_t)b * Ncols + c];
    }
    shS[ty][tx] = s;
    shQ[ty][tx] = q;
    __syncthreads();
    if (ty == 0) {
        float S = 0.f, Q = 0.f;
#pragma unroll
        for (int r = 0; r < 16; ++r) { S += shS[r][tx]; Q += shQ[r][tx]; }
        float m = S * inv_n;
        float var = Q * inv_n - m * m;
        float rs = rsqrtf(var + 1e-5f);
        float sc = gamma[c] * rs;
        scale[c] = sc;
        shift[c] = beta[c] - sc * m;
    }
}

// ---------------- BN2 apply + ReLU: x2 bf16 -> d_out fp32 (wide grid) ----------------
__global__ void bn2_apply_kernel(const u16* __restrict__ X, float* __restrict__ Y,
                                 const float* __restrict__ scale,
                                 const float* __restrict__ shift, int n8) {
    int i = blockIdx.x * blockDim.x + threadIdx.x;
    if (i >= n8) return;
    int c = (i & 15) << 3;
    float4 raw = ((const float4*)X)[i];
    const u16* xb = (const u16*)&raw;
    float4 sc0 = *(const float4*)(scale + c);
    float4 sc1 = *(const float4*)(scale + c + 4);
    float4 sh0 = *(const float4*)(shift + c);
    float4 sh1 = *(const float4*)(shift + c + 4);
    float4 y0, y1;
    y0.x = fmaxf(0.f, bf2f(xb[0]) * sc0.x + sh0.x);
    y0.y = fmaxf(0.f, bf2f(xb[1]) * sc0.y + sh0.y);
    y0.z = fmaxf(0.f, bf2f(xb[2]) * sc0.z + sh0.z);
    y0.w = fmaxf(0.f, bf2f(xb[3]) * sc0.w + sh0.w);
    y1.x = fmaxf(0.f, bf2f(xb[4]) * sc1.x + sh1.x);
    y1.y = fmaxf(0.f, bf2f(xb[5]) * sc1.y + sh1.y);
    y1.z = fmaxf(0.f, bf2f(xb[6]) * sc1.z + sh1.z);
    y1.w = fmaxf(0.f, bf2f(xb[7]) * sc1.w + sh1.w);
    ((float4*)Y)[i * 2]     = y0;
    ((float4*)Y)[i * 2 + 1] = y1;
}

extern "C" void kernel_launch(void* const* d_in, const int* in_sizes, int n_in,
                              void* d_out, int out_size, void* d_ws, size_t ws_size,
                              hipStream_t stream) {
    const float* v    = (const float*)d_in[0];
    const int* src    = (const int*)d_in[1];
    const int* dst    = (const int*)d_in[2];
    const float* ew   = (const float*)d_in[3];
    const float* eps  = (const float*)d_in[4];
    const float* W1   = (const float*)d_in[5];
    const float* b1   = (const float*)d_in[6];
    const float* g1   = (const float*)d_in[7];
    const float* be1  = (const float*)d_in[8];
    const float* W2   = (const float*)d_in[9];
    const float* b2   = (const float*)d_in[10];
    const float* g2   = (const float*)d_in[11];
    const float* be2  = (const float*)d_in[12];
    float* out = (float*)d_out;

    // ---- workspace layout (bytes) ----
    char* base = (char*)d_ws;
    u16* x1   = (u16*)(base);                      // [N,512] bf16
    u16* vbf  = (u16*)(base + 51200000ull);        // [N,128] bf16
    u16* vagg = (u16*)(base + 64000000ull);        // [N,128] bf16
    u16* x2   = (u16*)(base + 76800000ull);        // [N,128] bf16 raw pre-BN2
    u16* W1t  = (u16*)(base + 89600000ull);        // 512x128 bf16
    u16* W2t  = (u16*)(base + 89731072ull);        // 128x512 bf16
    float* psum   = (float*)(base + 89862144ull);  // [196][512] fp32 max
    float* psq    = (float*)(base + 90663168ull);  // [196][512] fp32 max
    float* scale1 = (float*)(base + 91464192ull);  // 512
    float* shift1 = scale1 + 512;
    float* scale2 = shift1 + 512;
    float* shift2 = scale2 + 128;
    int* counts     = (int*)(shift2 + 128);        // 50,000
    int* row_start  = counts + 50000;              // 50,001 (+pad 3)
    int* pos        = row_start + 50004;           // 800,000
    int2* csr_ew    = (int2*)(pos + 800000);       // 800,000 * 8 B
    int* block_sums = (int*)(csr_ew + 800000);     // 256

    hipMemsetAsync(counts, 0, (size_t)50000 * sizeof(int), stream);

    // CSR build + casts
    cast_v_kernel<<<(N_NODES * D_INF / 8 + 255) / 256, 256, 0, stream>>>(v, vbf);
    hist_kernel<<<(EQ + 255) / 256, 256, 0, stream>>>(dst, counts, pos);
    prep_weights_kernel<<<(128 * 512 + 255) / 256, 256, 0, stream>>>(W1, W2, W1t, W2t);
    reduce_kernel<<<SCAN_NB, 256, 0, stream>>>(counts, block_sums);
    scan_final<<<SCAN_NB, 256, 0, stream>>>(counts, block_sums, row_start);
    fill_kernel<<<(E_EDGES + 255) / 256, 256, 0, stream>>>(src, dst, ew, pos, row_start, csr_ew);
    gather_kernel<<<(N_NODES + 15) / 16, 256, 0, stream>>>(vbf, row_start, csr_ew, eps, vagg);

    // GEMM1: x1 = vagg @ W1 + b1 (bf16 raw) + BN1 partials — 256x128 tile
    {
        dim3 grid(D_HIDF / 128, MBLKS);
        mfma_gemm_bn<256, 128, 0><<<grid, 512, 0, stream>>>(vagg, W1t, b1, nullptr, nullptr,
                                                            x1, psum, psq, N_NODES, D_HIDF, D_INF);
    }
    bn_finalize_kernel<<<D_HIDF / 64, dim3(64, 16), 0, stream>>>(
        psum, psq, g1, be1, scale1, shift1, MBLKS, D_HIDF, 1.0f / N_NODES);

    // GEMM2: x2 = relu(bn1(x1)) @ W2 + b2 (bf16 raw) + BN2 partials — 256x64 tile
    {
        dim3 grid(D_OUTF / 64, MBLKS);
        mfma_gemm_bn<256, 64, 1><<<grid, 512, 0, stream>>>(x1, W2t, b2, scale1, shift1,
                                                           x2, psum, psq, N_NODES, D_OUTF, D_HIDF);
    }
    bn_finalize_kernel<<<D_OUTF / 64, dim3(64, 16), 0, stream>>>(
        psum, psq, g2, be2, scale2, shift2, MBLKS, D_OUTF, 1.0f / N_NODES);

    // BN2 apply + ReLU: x2 (bf16) -> d_out (fp32)
    {
        int n8 = N_NODES * D_OUTF / 8;
        bn2_apply_kernel<<<(n8 + 255) / 256, 256, 0, stream>>>(x2, out, scale2, shift2, n8);
    }
}